// Round 2
// baseline (7271.494 us; speedup 1.0000x reference)
//
#include <hip/hip_runtime.h>

typedef unsigned short u16;
typedef __bf16 bh8 __attribute__((ext_vector_type(8)));
typedef float f32x4 __attribute__((ext_vector_type(4)));

#define cD   1024
#define cN   2048
#define cH   8
#define cDK  128
#define cDFF 4096
#define cL   4
#define LAM_ 0.08838834764831845f  /* 1/sqrt(128) */

__device__ __forceinline__ u16 f2bf(float f) {
    union { float f; unsigned u; } x; x.f = f;
    unsigned r = x.u + 0x7fffu + ((x.u >> 16) & 1u);  // RNE
    return (u16)(r >> 16);
}
__device__ __forceinline__ float bf2f(u16 h) {
    union { unsigned u; float f; } x; x.u = ((unsigned)h) << 16;
    return x.f;
}
// split x into hi + lo bf16 (lo = exact residual rounded; total rel err ~2^-17)
__device__ __forceinline__ void split_bf(float v, u16& h, u16& l) {
    h = f2bf(v);
    l = f2bf(v - bf2f(h));
}

// ---------------- elementwise helpers ----------------
__global__ void copy_f32(const float* __restrict__ s, float* __restrict__ d, int n) {
    int i = blockIdx.x * 256 + threadIdx.x;
    if (i < n) d[i] = s[i];
}

__global__ void cast_split_k(const float* __restrict__ s, u16* __restrict__ h,
                             u16* __restrict__ l, int n) {
    int i = blockIdx.x * 256 + threadIdx.x;
    if (i < n) { u16 a, b; split_bf(s[i], a, b); h[i] = a; l[i] = b; }
}

// X [D,N] fp32 row-major -> XT [N,D] split bf16
__global__ void cast_transpose_split(const float* __restrict__ X, u16* __restrict__ h,
                                     u16* __restrict__ l, int D_, int N_) {
    long i = (long)blockIdx.x * 256 + threadIdx.x;
    if (i < (long)D_ * N_) {
        int d = (int)(i / N_), n = (int)(i % N_);
        u16 a, b; split_bf(X[i], a, b);
        h[(long)n * D_ + d] = a;
        l[(long)n * D_ + d] = b;
    }
}

// row-wise softmax on S [rows x Ncols] fp32, write split bf16 P
__global__ void softmax_rows(const float* __restrict__ S, u16* __restrict__ Ph,
                             u16* __restrict__ Pl, int Ncols) {
    const long base = (long)blockIdx.x * Ncols;
    const float* s = S + base;
    __shared__ float red[256];
    const int tid = threadIdx.x;
    float mx = -1e30f;
    for (int c = tid; c < Ncols; c += 256) mx = fmaxf(mx, s[c]);
    red[tid] = mx; __syncthreads();
    for (int w = 128; w > 0; w >>= 1) {
        if (tid < w) red[tid] = fmaxf(red[tid], red[tid + w]);
        __syncthreads();
    }
    mx = red[0]; __syncthreads();
    float sum = 0.f;
    for (int c = tid; c < Ncols; c += 256) sum += __expf(s[c] - mx);
    red[tid] = sum; __syncthreads();
    for (int w = 128; w > 0; w >>= 1) {
        if (tid < w) red[tid] += red[tid + w];
        __syncthreads();
    }
    const float inv = 1.0f / red[0];
    for (int c = tid; c < Ncols; c += 256) {
        u16 a, b; split_bf(__expf(s[c] - mx) * inv, a, b);
        Ph[base + c] = a; Pl[base + c] = b;
    }
}

// ---- split-precision GEMM: C[M,N] = alpha * (Ah+Al)[M,K] * (Bh+Bl)[N,K]^T ----
// acc += Ah*Bh + Ah*Bl + Al*Bh  (lo*lo dropped, ~2^-18 rel — negligible)
// fp32 out (Cf, optional +=) or split-bf16 out (Cbh/Cbl).
// Requires M%128==0, N%128==0, K%32==0 (true for every call here).
__global__ __launch_bounds__(256)
void gemm_split(const u16* __restrict__ Ah, const u16* __restrict__ Al,
                const u16* __restrict__ Bh, const u16* __restrict__ Bl,
                float* __restrict__ Cf, u16* __restrict__ Cbh, u16* __restrict__ Cbl,
                int M, int N, int K,
                long bsA, long bsB, long bsC,
                float alpha, int accumulate, int relu,
                const float* __restrict__ biasM, const float* __restrict__ biasN)
{
    const int bz = blockIdx.z;
    Ah += (long)bz * bsA; Al += (long)bz * bsA;
    Bh += (long)bz * bsB; Bl += (long)bz * bsB;

    __shared__ __align__(16) u16 Ash[128 * 40];
    __shared__ __align__(16) u16 Asl[128 * 40];
    __shared__ __align__(16) u16 Bsh[128 * 40];
    __shared__ __align__(16) u16 Bsl[128 * 40];

    const int tid  = threadIdx.x;
    const int lane = tid & 63;
    const int wave = tid >> 6;
    const int wm = (wave >> 1) * 64;
    const int wn = (wave & 1) * 64;
    const int m0 = blockIdx.y * 128;
    const int n0 = blockIdx.x * 128;

    const int lrow = tid >> 2;       // 0..63
    const int lk   = (tid & 3) * 8;  // 0,8,16,24

    f32x4 acc[4][4];
#pragma unroll
    for (int i = 0; i < 4; ++i)
#pragma unroll
        for (int j = 0; j < 4; ++j)
            acc[i][j] = f32x4{0.f, 0.f, 0.f, 0.f};

    const int q = lane >> 4;
    const int r = lane & 15;

    for (int k0 = 0; k0 < K; k0 += 32) {
#pragma unroll
        for (int p = 0; p < 2; ++p) {
            const int row = lrow + p * 64;
            const long offA = (long)(m0 + row) * K + k0 + lk;
            const long offB = (long)(n0 + row) * K + k0 + lk;
            *(int4*)(Ash + row * 40 + lk) = *(const int4*)(Ah + offA);
            *(int4*)(Asl + row * 40 + lk) = *(const int4*)(Al + offA);
            *(int4*)(Bsh + row * 40 + lk) = *(const int4*)(Bh + offB);
            *(int4*)(Bsl + row * 40 + lk) = *(const int4*)(Bl + offB);
        }
        __syncthreads();

        bh8 afh[4], afl[4], bfh[4], bfl[4];
#pragma unroll
        for (int i = 0; i < 4; ++i) {
            afh[i] = *(const bh8*)(Ash + (wm + i * 16 + r) * 40 + q * 8);
            afl[i] = *(const bh8*)(Asl + (wm + i * 16 + r) * 40 + q * 8);
        }
#pragma unroll
        for (int j = 0; j < 4; ++j) {
            bfh[j] = *(const bh8*)(Bsh + (wn + j * 16 + r) * 40 + q * 8);
            bfl[j] = *(const bh8*)(Bsl + (wn + j * 16 + r) * 40 + q * 8);
        }
#pragma unroll
        for (int i = 0; i < 4; ++i)
#pragma unroll
            for (int j = 0; j < 4; ++j) {
                acc[i][j] = __builtin_amdgcn_mfma_f32_16x16x32_bf16(afh[i], bfh[j], acc[i][j], 0, 0, 0);
                acc[i][j] = __builtin_amdgcn_mfma_f32_16x16x32_bf16(afh[i], bfl[j], acc[i][j], 0, 0, 0);
                acc[i][j] = __builtin_amdgcn_mfma_f32_16x16x32_bf16(afl[i], bfh[j], acc[i][j], 0, 0, 0);
            }
        __syncthreads();
    }

    // epilogue: C/D layout col=lane&15, row=(lane>>4)*4+t  [verified m89/m91]
#pragma unroll
    for (int i = 0; i < 4; ++i) {
#pragma unroll
        for (int j = 0; j < 4; ++j) {
            const int col = n0 + wn + j * 16 + r;
#pragma unroll
            for (int t = 0; t < 4; ++t) {
                const int row = m0 + wm + i * 16 + q * 4 + t;
                float v = acc[i][j][t] * alpha;
                if (biasM) v += biasM[row];
                if (biasN) v += biasN[col];
                if (relu)  v = fmaxf(v, 0.f);
                const long idx = (long)bz * bsC + (long)row * N + col;
                if (Cf) {
                    float o = accumulate ? Cf[idx] : 0.f;
                    Cf[idx] = o + v;
                } else {
                    u16 a, b; split_bf(v, a, b);
                    Cbh[idx] = a; Cbl[idx] = b;
                }
            }
        }
    }
}

// ---------------- host ----------------
static inline void launch_gemm(hipStream_t st,
                               const u16* Ah, const u16* Al,
                               const u16* Bh, const u16* Bl,
                               float* Cf, u16* Cbh, u16* Cbl,
                               int M, int N, int K,
                               long bsA, long bsB, long bsC, int batch,
                               float alpha, int accumulate, int relu,
                               const float* biasM, const float* biasN)
{
    dim3 grid(N / 128, M / 128, batch), block(256);
    gemm_split<<<grid, block, 0, st>>>(Ah, Al, Bh, Bl, Cf, Cbh, Cbl,
                                       M, N, K, bsA, bsB, bsC,
                                       alpha, accumulate, relu, biasM, biasN);
}

extern "C" void kernel_launch(void* const* d_in, const int* in_sizes, int n_in,
                              void* d_out, int out_size, void* d_ws, size_t ws_size,
                              hipStream_t stream)
{
    const float* Xin = (const float*)d_in[0];
    const float* Qw  = (const float*)d_in[1];
    const float* Kw  = (const float*)d_in[2];
    const float* Vw  = (const float*)d_in[3];
    const float* W1w = (const float*)d_in[4];
    const float* b1w = (const float*)d_in[5];
    const float* W2w = (const float*)d_in[6];
    const float* b2w = (const float*)d_in[7];
    float* Xf = (float*)d_out;  // running X, fp32 [D,N]

    // ---- workspace carve with phase aliasing (total ~76 MiB) ----
    char* base = (char*)d_ws;
    size_t off = 0;
    auto carve = [&](size_t bytes) {
        char* p = base + off; off = (off + bytes + 255) & ~(size_t)255; return p;
    };
    // persistent within a layer
    u16* XbT_h = (u16*)carve((size_t)cN * cD * 2);
    u16* XbT_l = (u16*)carve((size_t)cN * cD * 2);
    const size_t phase0 = off;

    // attention-phase scratch
    u16*   QXT_h = (u16*)carve((size_t)cH * cN * cDK * 2);
    u16*   QXT_l = (u16*)carve((size_t)cH * cN * cDK * 2);
    u16*   KXT_h = (u16*)carve((size_t)cH * cN * cDK * 2);
    u16*   KXT_l = (u16*)carve((size_t)cH * cN * cDK * 2);
    float* ST    = (float*)carve((size_t)cN * cN * 4);
    u16*   P_h   = (u16*)carve((size_t)cN * cN * 2);
    u16*   P_l   = (u16*)carve((size_t)cN * cN * 2);
    u16*   VX_h  = (u16*)carve((size_t)cD * cN * 2);
    u16*   VX_l  = (u16*)carve((size_t)cD * cN * 2);
    u16*   Qb_h  = (u16*)carve((size_t)cH * cDK * cD * 2);
    u16*   Qb_l  = (u16*)carve((size_t)cH * cDK * cD * 2);
    u16*   Kb_h  = (u16*)carve((size_t)cH * cDK * cD * 2);
    u16*   Kb_l  = (u16*)carve((size_t)cH * cDK * cD * 2);
    u16*   Vb_h  = (u16*)carve((size_t)cD * cD * 2);
    u16*   Vb_l  = (u16*)carve((size_t)cD * cD * 2);

    // FFN-phase scratch (aliases attention scratch — disjoint live ranges)
    off = phase0;
    u16* H1_h = (u16*)carve((size_t)cN * cDFF * 2);
    u16* H1_l = (u16*)carve((size_t)cN * cDFF * 2);
    u16* W1_h = (u16*)carve((size_t)cDFF * cD * 2);
    u16* W1_l = (u16*)carve((size_t)cDFF * cD * 2);
    u16* W2_h = (u16*)carve((size_t)cD * cDFF * 2);
    u16* W2_l = (u16*)carve((size_t)cD * cDFF * 2);

    const int nX = cD * cN;  // 2097152
    copy_f32<<<dim3((nX + 255) / 256), dim3(256), 0, stream>>>(Xin, Xf, nX);

    for (int l = 0; l < cL; ++l) {
        // X^T split bf16 (pre-attention X)
        cast_transpose_split<<<dim3((nX + 255) / 256), dim3(256), 0, stream>>>(
            Xf, XbT_h, XbT_l, cD, cN);

        // cast this layer's Q,K weights
        const int nQK = cH * cDK * cD;  // 1048576
        cast_split_k<<<dim3((nQK + 255) / 256), dim3(256), 0, stream>>>(
            Qw + (long)l * nQK, Qb_h, Qb_l, nQK);
        cast_split_k<<<dim3((nQK + 255) / 256), dim3(256), 0, stream>>>(
            Kw + (long)l * nQK, Kb_h, Kb_l, nQK);

        // QXT[h][n,k] = sum_d X[d,n] Q[h,k,d]   (batched over heads)
        launch_gemm(stream, XbT_h, XbT_l, Qb_h, Qb_l, nullptr, QXT_h, QXT_l,
                    cN, cDK, cD, 0, (long)cDK * cD, (long)cN * cDK, cH,
                    1.f, 0, 0, nullptr, nullptr);
        launch_gemm(stream, XbT_h, XbT_l, Kb_h, Kb_l, nullptr, KXT_h, KXT_l,
                    cN, cDK, cD, 0, (long)cDK * cD, (long)cN * cDK, cH,
                    1.f, 0, 0, nullptr, nullptr);

        for (int h = 0; h < cH; ++h) {
            const long ho = (long)h * cN * cDK;
            // ST[m,n] = LAM * sum_k KX[k,m] QX[k,n]  (scores^T -> row softmax)
            launch_gemm(stream, KXT_h + ho, KXT_l + ho, QXT_h + ho, QXT_l + ho,
                        ST, nullptr, nullptr, cN, cN, cDK,
                        0, 0, 0, 1, LAM_, 0, 0, nullptr, nullptr);
            softmax_rows<<<dim3(cN), dim3(256), 0, stream>>>(ST, P_h, P_l, cN);
            // VX[h] = V[l,h] @ X : [D,N]
            const int nV = cD * cD;
            cast_split_k<<<dim3((nV + 255) / 256), dim3(256), 0, stream>>>(
                Vw + ((long)l * cH + h) * nV, Vb_h, Vb_l, nV);
            launch_gemm(stream, Vb_h, Vb_l, XbT_h, XbT_l, nullptr, VX_h, VX_l,
                        cD, cN, cD, 0, 0, 0, 1, 1.f, 0, 0, nullptr, nullptr);
            // X[e,m] += sum_n VX[e,n] P[m,n]   (residual + head-sum)
            launch_gemm(stream, VX_h, VX_l, P_h, P_l, Xf, nullptr, nullptr,
                        cD, cN, cN, 0, 0, 0, 1, 1.f, 1, 0, nullptr, nullptr);
        }

        // FFN on post-attention X
        cast_transpose_split<<<dim3((nX + 255) / 256), dim3(256), 0, stream>>>(
            Xf, XbT_h, XbT_l, cD, cN);
        const int nW = cDFF * cD;  // 4194304
        cast_split_k<<<dim3((nW + 255) / 256), dim3(256), 0, stream>>>(
            W1w + (long)l * nW, W1_h, W1_l, nW);
        // H1T[m,f] = relu(sum_d X[d,m] W1[f,d] + b1[f])
        launch_gemm(stream, XbT_h, XbT_l, W1_h, W1_l, nullptr, H1_h, H1_l,
                    cN, cDFF, cD, 0, 0, 0, 1, 1.f, 0, 1,
                    nullptr, b1w + (long)l * cDFF);
        cast_split_k<<<dim3((nW + 255) / 256), dim3(256), 0, stream>>>(
            W2w + (long)l * nW, W2_h, W2_l, nW);
        // X[e,m] += sum_f W2[e,f] H1T[m,f] + b2[e]
        launch_gemm(stream, W2_h, W2_l, H1_h, H1_l, Xf, nullptr, nullptr,
                    cD, cN, cDFF, 0, 0, 0, 1, 1.f, 1, 0,
                    b2w + (long)l * cD, nullptr);
    }
    (void)in_sizes; (void)n_in; (void)out_size; (void)ws_size;
}

// Round 3
// 3115.602 us; speedup vs baseline: 2.3339x; 2.3339x over previous
//
#include <hip/hip_runtime.h>

typedef unsigned short u16;
typedef __bf16 bh8 __attribute__((ext_vector_type(8)));
typedef float f32x4 __attribute__((ext_vector_type(4)));

#define cD   1024
#define cN   2048
#define cH   8
#define cDK  128
#define cDFF 4096
#define cL   4
#define LAM_ 0.08838834764831845f  /* 1/sqrt(128) */

__device__ __forceinline__ u16 f2bf(float f) {
    union { float f; unsigned u; } x; x.f = f;
    unsigned r = x.u + 0x7fffu + ((x.u >> 16) & 1u);  // RNE
    return (u16)(r >> 16);
}
__device__ __forceinline__ float bf2f(u16 h) {
    union { unsigned u; float f; } x; x.u = ((unsigned)h) << 16;
    return x.f;
}
__device__ __forceinline__ void split_bf(float v, u16& h, u16& l) {
    h = f2bf(v);
    l = f2bf(v - bf2f(h));
}

// async global->LDS, 16 B per lane; lds dest must be wave-uniform base (lane L lands at base + L*16)
__device__ __forceinline__ void async_cp16(const u16* gsrc, u16* ldst) {
    __builtin_amdgcn_global_load_lds(
        (const __attribute__((address_space(1))) unsigned int*)gsrc,
        (__attribute__((address_space(3))) unsigned int*)(unsigned int)(unsigned long long)ldst,
        16, 0, 0);
}

// ---------------- elementwise helpers ----------------
// split-cast fp32 -> (hi,lo) bf16, 4 elems/thread
__global__ void cast_split4(const float* __restrict__ s, u16* __restrict__ h,
                            u16* __restrict__ l, int n4) {
    int i = blockIdx.x * 256 + threadIdx.x;
    if (i < n4) {
        float4 v = ((const float4*)s)[i];
        ushort4 hh, ll;
        split_bf(v.x, hh.x, ll.x);
        split_bf(v.y, hh.y, ll.y);
        split_bf(v.z, hh.z, ll.z);
        split_bf(v.w, hh.w, ll.w);
        ((ushort4*)h)[i] = hh;
        ((ushort4*)l)[i] = ll;
    }
}

// in[R][C] -> out[C][R], LDS-tiled 32x32 (coalesced both sides)
__global__ __launch_bounds__(256)
void transpose_f32(const float* __restrict__ in, float* __restrict__ out, int R, int C) {
    __shared__ float t[32][33];
    const int bx = blockIdx.x * 32;  // C
    const int by = blockIdx.y * 32;  // R
    const int tx = threadIdx.x & 31, ty = threadIdx.x >> 5;
#pragma unroll
    for (int yy = 0; yy < 32; yy += 8)
        t[ty + yy][tx] = in[(long)(by + ty + yy) * C + bx + tx];
    __syncthreads();
#pragma unroll
    for (int yy = 0; yy < 32; yy += 8)
        out[(long)(bx + ty + yy) * R + by + tx] = t[tx][ty + yy];
}

// online softmax over rows of length 2048; S fp32 -> split-bf16 P
__global__ __launch_bounds__(256)
void softmax_rows(const float* __restrict__ S, u16* __restrict__ Ph, u16* __restrict__ Pl) {
    const long base = (long)blockIdx.x * cN;
    const float4* s4 = (const float4*)(S + base);
    const int tid = threadIdx.x;
    float m = -3.0e38f, l = 0.f;
    for (int c = tid; c < cN / 4; c += 256) {
        float4 v = s4[c];
        float mx = fmaxf(fmaxf(v.x, v.y), fmaxf(v.z, v.w));
        if (mx > m) { l *= __expf(m - mx); m = mx; }
        l += __expf(v.x - m) + __expf(v.y - m) + __expf(v.z - m) + __expf(v.w - m);
    }
    __shared__ float rm[256], rl[256];
    rm[tid] = m; rl[tid] = l; __syncthreads();
    for (int w = 128; w > 0; w >>= 1) {
        if (tid < w) {
            float m2 = rm[tid + w], l2 = rl[tid + w];
            float mm = fmaxf(rm[tid], m2);
            rl[tid] = rl[tid] * __expf(rm[tid] - mm) + l2 * __expf(m2 - mm);
            rm[tid] = mm;
        }
        __syncthreads();
    }
    m = rm[0];
    const float inv = 1.0f / rl[0];
    for (int c = tid; c < cN / 4; c += 256) {
        float4 v = s4[c];
        ushort4 hh, ll;
        split_bf(__expf(v.x - m) * inv, hh.x, ll.x);
        split_bf(__expf(v.y - m) * inv, hh.y, ll.y);
        split_bf(__expf(v.z - m) * inv, hh.z, ll.z);
        split_bf(__expf(v.w - m) * inv, hh.w, ll.w);
        ((ushort4*)(Ph + base))[c] = hh;
        ((ushort4*)(Pl + base))[c] = ll;
    }
}

// ---- split-precision GEMM: C[M,N] = alpha*(Ah+Al)[M,K]*(Bh+Bl)[N,K]^T (+biasN)(relu) ----
// mode: 0 = split-bf16 write, 1 = fp32 write, 3 = fp32 atomicAdd (split-K safe)
// z = (g, s): g batch index (strides bsA/bsB/bsC), s split-K slice (col offset s*K)
// async global_load_lds staging, XOR-swizzled LDS (2-way conflicts only)
__global__ __launch_bounds__(256)
void gemm_split(const u16* __restrict__ Ah, const u16* __restrict__ Al, int lda, long bsA,
                const u16* __restrict__ Bh, const u16* __restrict__ Bl, int ldb, long bsB,
                float* __restrict__ Cf, u16* __restrict__ Cbh, u16* __restrict__ Cbl,
                int ldc, long bsC,
                int M, int N, int K, int SK,
                float alpha, int mode, int relu, const float* __restrict__ biasN)
{
    const int g = blockIdx.z / SK;
    const int s = blockIdx.z % SK;
    const long za = (long)g * bsA + (long)s * K;
    const long zb = (long)g * bsB + (long)s * K;
    Ah += za; Al += za; Bh += zb; Bl += zb;
    if (s != 0) biasN = nullptr;

    __shared__ __align__(16) u16 Ash[128 * 32];
    __shared__ __align__(16) u16 Asl[128 * 32];
    __shared__ __align__(16) u16 Bsh[128 * 32];
    __shared__ __align__(16) u16 Bsl[128 * 32];

    const int tid  = threadIdx.x;
    const int lane = tid & 63;
    const int wave = tid >> 6;
    const int wm = (wave >> 1) * 64;
    const int wn = (wave & 1) * 64;
    const int m0 = blockIdx.y * 128;
    const int n0 = blockIdx.x * 128;

    // staging lane-statics: chunk c covers rows c*16..+15; lane L -> row c*16+L/4,
    // LDS slot L%4; slot holds global col-group (slot ^ (row&3))  [XOR swizzle]
    const int srow = lane >> 2;                       // 0..15
    const int scol = (((lane & 3) ^ (srow & 3)) * 8); // swizzled source col
    // fragment lane-statics
    const int q = lane >> 4;
    const int r = lane & 15;
    const int fcol = ((q ^ (r & 3)) * 8);             // swizzled read col

    f32x4 acc[4][4];
#pragma unroll
    for (int i = 0; i < 4; ++i)
#pragma unroll
        for (int j = 0; j < 4; ++j)
            acc[i][j] = f32x4{0.f, 0.f, 0.f, 0.f};

    for (int k0 = 0; k0 < K; k0 += 32) {
#pragma unroll
        for (int p = 0; p < 2; ++p) {
            const int c = p * 4 + wave;          // chunk 0..7, wave-uniform
            const int grow = c * 16 + srow;      // tile row
            const long aoff = (long)(m0 + grow) * lda + k0 + scol;
            const long boff = (long)(n0 + grow) * ldb + k0 + scol;
            u16* la = Ash + c * 512;  // lane L lands at +L*8 elems
            u16* lb = Bsh + c * 512;
            async_cp16(Ah + aoff, la);
            async_cp16(Al + aoff, Asl + c * 512);
            async_cp16(Bh + boff, lb);
            async_cp16(Bl + boff, Bsl + c * 512);
        }
        __syncthreads();

        bh8 afh[4], afl[4], bfh[4], bfl[4];
#pragma unroll
        for (int i = 0; i < 4; ++i) {
            const int ra = (wm + i * 16 + r) * 32 + fcol;
            afh[i] = *(const bh8*)(Ash + ra);
            afl[i] = *(const bh8*)(Asl + ra);
        }
#pragma unroll
        for (int j = 0; j < 4; ++j) {
            const int rb = (wn + j * 16 + r) * 32 + fcol;
            bfh[j] = *(const bh8*)(Bsh + rb);
            bfl[j] = *(const bh8*)(Bsl + rb);
        }
#pragma unroll
        for (int i = 0; i < 4; ++i)
#pragma unroll
            for (int j = 0; j < 4; ++j) {
                acc[i][j] = __builtin_amdgcn_mfma_f32_16x16x32_bf16(afh[i], bfh[j], acc[i][j], 0, 0, 0);
                acc[i][j] = __builtin_amdgcn_mfma_f32_16x16x32_bf16(afh[i], bfl[j], acc[i][j], 0, 0, 0);
                acc[i][j] = __builtin_amdgcn_mfma_f32_16x16x32_bf16(afl[i], bfh[j], acc[i][j], 0, 0, 0);
            }
        __syncthreads();
    }

    // C/D layout: col=lane&15, row=(lane>>4)*4+t  [verified m89/m91]
#pragma unroll
    for (int i = 0; i < 4; ++i) {
#pragma unroll
        for (int j = 0; j < 4; ++j) {
            const int col = n0 + wn + j * 16 + r;
#pragma unroll
            for (int t = 0; t < 4; ++t) {
                const int row = m0 + wm + i * 16 + q * 4 + t;
                float v = acc[i][j][t] * alpha;
                if (biasN) v += biasN[col];
                if (relu)  v = fmaxf(v, 0.f);
                const long idx = (long)g * bsC + (long)row * ldc + col;
                if (mode == 0) {
                    u16 a, b; split_bf(v, a, b);
                    Cbh[idx] = a; Cbl[idx] = b;
                } else if (mode == 1) {
                    Cf[idx] = v;
                } else {
                    unsafeAtomicAdd(&Cf[idx], v);
                }
            }
        }
    }
}

// ---------------- host ----------------
static inline void launch_gemm(hipStream_t st,
                               const u16* Ah, const u16* Al, int lda, long bsA,
                               const u16* Bh, const u16* Bl, int ldb, long bsB,
                               float* Cf, u16* Cbh, u16* Cbl, int ldc, long bsC,
                               int M, int N, int K, int Gz, int SK,
                               float alpha, int mode, int relu, const float* biasN)
{
    dim3 grid(N / 128, M / 128, Gz * SK), block(256);
    gemm_split<<<grid, block, 0, st>>>(Ah, Al, lda, bsA, Bh, Bl, ldb, bsB,
                                       Cf, Cbh, Cbl, ldc, bsC,
                                       M, N, K, SK, alpha, mode, relu, biasN);
}

static inline void launch_cast(hipStream_t st, const float* s, u16* h, u16* l, long n) {
    int n4 = (int)(n / 4);
    cast_split4<<<dim3((n4 + 255) / 256), dim3(256), 0, st>>>(s, h, l, n4);
}

extern "C" void kernel_launch(void* const* d_in, const int* in_sizes, int n_in,
                              void* d_out, int out_size, void* d_ws, size_t ws_size,
                              hipStream_t stream)
{
    const float* Xin = (const float*)d_in[0];
    const float* Qw  = (const float*)d_in[1];
    const float* Kw  = (const float*)d_in[2];
    const float* Vw  = (const float*)d_in[3];
    const float* W1w = (const float*)d_in[4];
    const float* b1w = (const float*)d_in[5];
    const float* W2w = (const float*)d_in[6];
    const float* b2w = (const float*)d_in[7];
    float* Xout = (float*)d_out;

    // ---- adaptive head-group size from ws_size ----
    // total(G) = 33.55 MB fixed + max(G*46.14 MB, 50.33 MB)
    int G = 1;
    if      (ws_size >= 402653184ull + 1048576) G = 8;
    else if (ws_size >= 218103808ull + 1048576) G = 4;
    else if (ws_size >= 125829120ull + 1048576) G = 2;

    // ---- workspace carve ----
    char* base = (char*)d_ws;
    size_t off = 0;
    auto carve = [&](size_t bytes) {
        char* p = base + off; off = (off + bytes + 255) & ~(size_t)255; return p;
    };
    float* Xt     = (float*)carve((size_t)cN * cD * 4);   // running X^T [N,D] fp32
    u16*   XbT_h  = (u16*)carve((size_t)cN * cD * 2);
    u16*   XbT_l  = (u16*)carve((size_t)cN * cD * 2);
    // R1: QKXT' [2][N][D] split  |  FFN: W1 split
    u16*   QKXT_h = (u16*)carve((size_t)2 * cN * cD * 2);
    u16*   QKXT_l = (u16*)carve((size_t)2 * cN * cD * 2);
    u16*   W1_h   = QKXT_h;  // alias (disjoint live ranges)
    u16*   W1_l   = QKXT_l;
    // R2
    const size_t r2 = off;
    float* ST   = (float*)carve((size_t)G * cN * cN * 4);
    u16*   P_h  = (u16*)carve((size_t)G * cN * cN * 2);
    u16*   P_l  = (u16*)carve((size_t)G * cN * cN * 2);
    u16*   Vb_h = (u16*)carve((size_t)G * cD * cD * 2);
    u16*   Vb_l = (u16*)carve((size_t)G * cD * cD * 2);
    u16*   VX_h = (u16*)carve((size_t)G * cD * cN * 2);
    u16*   VX_l = (u16*)carve((size_t)G * cD * cN * 2);
    // aliases into R2 front: QK weight casts (dead before group loop starts)
    off = r2;
    u16*   QKb_h = (u16*)carve((size_t)2 * cH * cDK * cD * 2);
    u16*   QKb_l = (u16*)carve((size_t)2 * cH * cDK * cD * 2);
    // aliases into R2: FFN scratch (attention scratch dead by then)
    off = r2;
    u16*   H1_h = (u16*)carve((size_t)cN * cDFF * 2);
    u16*   H1_l = (u16*)carve((size_t)cN * cDFF * 2);
    u16*   W2_h = (u16*)carve((size_t)cD * cDFF * 2);
    u16*   W2_l = (u16*)carve((size_t)cD * cDFF * 2);

    const u16* QXT_h = QKXT_h;                 // slice 0
    const u16* QXT_l = QKXT_l;
    const u16* KXT_h = QKXT_h + (size_t)cN * cD;  // slice 1
    const u16* KXT_l = QKXT_l + (size_t)cN * cD;

    // ---- init: Xt = Xin^T ----
    transpose_f32<<<dim3(cN / 32, cD / 32), dim3(256), 0, stream>>>(Xin, Xt, cD, cN);

    const int SKy = (G >= 4) ? 1 : (G == 2 ? 2 : 4);  // Y GEMM split-K -> >=512 blocks

    for (int l = 0; l < cL; ++l) {
        // X^T split-cast (pre-attention)
        launch_cast(stream, Xt, XbT_h, XbT_l, (long)cN * cD);

        // Q,K weights -> contiguous [2][H*DK][D] split
        const long nQK = (long)cH * cDK * cD;  // 1048576
        launch_cast(stream, Qw + (long)l * nQK, QKb_h, QKb_l, nQK);
        launch_cast(stream, Kw + (long)l * nQK, QKb_h + nQK, QKb_l + nQK, nQK);

        // QKXT'[z][n][h*128+k] = sum_d X[d,n] {Q,K}[h,k,d]   (z=2)
        launch_gemm(stream, XbT_h, XbT_l, cD, 0,
                    QKb_h, QKb_l, cD, nQK,
                    nullptr, QKXT_h, QKXT_l, cD, (long)cN * cD,
                    cN, cD, cD, 2, 1, 1.f, 0, 0, nullptr);

        for (int g0 = 0; g0 < cH; g0 += G) {
            // ST[z][m][n] = LAM * sum_k KX[k,m] QX[k,n]  (z over heads in group)
            launch_gemm(stream, KXT_h + (long)g0 * cDK, KXT_l + (long)g0 * cDK, cD, cDK,
                        QXT_h + (long)g0 * cDK, QXT_l + (long)g0 * cDK, cD, cDK,
                        ST, nullptr, nullptr, cN, (long)cN * cN,
                        cN, cN, cDK, G, 1, LAM_, 1, 0, nullptr);
            softmax_rows<<<dim3(G * cN), dim3(256), 0, stream>>>(ST, P_h, P_l);

            // V weights for this group
            const long nV = (long)cD * cD;
            launch_cast(stream, Vw + ((long)l * cH + g0) * nV, Vb_h, Vb_l, (long)G * nV);
            // VX[z][e][n] = sum_d V[e,d] X[d,n]
            launch_gemm(stream, Vb_h, Vb_l, cD, nV,
                        XbT_h, XbT_l, cD, 0,
                        nullptr, VX_h, VX_l, cN, (long)cD * cN,
                        cD, cN, cD, G, 1, 1.f, 0, 0, nullptr);
            // Xt[m][e] += sum_n P[m,n] VX[e,n]   (atomic: heads + split-K race-safe)
            launch_gemm(stream, P_h, P_l, cN, (long)cN * cN,
                        VX_h, VX_l, cN, (long)cD * cN,
                        Xt, nullptr, nullptr, cD, 0,
                        cN, cD, cN / SKy, G, SKy, 1.f, 3, 0, nullptr);
        }

        // FFN (post-attention X)
        launch_cast(stream, Xt, XbT_h, XbT_l, (long)cN * cD);
        const long nW = (long)cDFF * cD;  // 4194304
        launch_cast(stream, W1w + (long)l * nW, W1_h, W1_l, nW);
        // H1[m][f] = relu(sum_d X[d,m] W1[f,d] + b1[f])
        launch_gemm(stream, XbT_h, XbT_l, cD, 0,
                    W1_h, W1_l, cD, 0,
                    nullptr, H1_h, H1_l, cDFF, 0,
                    cN, cDFF, cD, 1, 1, 1.f, 0, 1, b1w + (long)l * cDFF);
        launch_cast(stream, W2w + (long)l * nW, W2_h, W2_l, nW);
        // Xt[m][e] += sum_f H1[m,f] W2[e,f] + b2[e]   (split-K=4, atomic; bias on s==0 only)
        launch_gemm(stream, H1_h, H1_l, cDFF, 0,
                    W2_h, W2_l, cDFF, 0,
                    Xt, nullptr, nullptr, cD, 0,
                    cN, cD, cDFF / 4, 1, 4, 1.f, 3, 0, b2w + (long)l * cD);
    }

    // out[d][n] = Xt[n][d]
    transpose_f32<<<dim3(cD / 32, cN / 32), dim3(256), 0, stream>>>(Xt, Xout, cN, cD);

    (void)in_sizes; (void)n_in; (void)out_size;
}